// Round 1
// 7922.807 us; speedup vs baseline: 1.2774x; 1.2774x over previous
//
#include <hip/hip_runtime.h>

typedef unsigned int uint;
typedef unsigned short ushort;
typedef unsigned long long u64;
typedef __attribute__((ext_vector_type(8))) __bf16 bf16x8;
typedef __attribute__((ext_vector_type(4))) float floatx4;

// ---- output layout (fp32 elements) ----
#define OFF_HN   16777216u   // out: (512,32,1024)
#define OFF_CN   16809984u
#define OFF_X    16842752u   // x:   (512,32,512), row = t*32+b
#define OFF_LENS 25231360u

// ---- workspace layout (bytes) ----
#define WS_ORD   4096u       // [0,4096): barrier flags (2 dirs x 16 WGs x 128B)
#define WS_LENSB 4224u
#define WS_HBUF  8192u       // 2 dirs x 2 bufs x 32x512 bf16 = 131072 B
#define WS_XBF   262144u     // optional bf16 copy of x: 16384*512*2 = 16 MiB

__device__ __forceinline__ ushort f2bf(float f){
  uint u = __float_as_uint(f);
  u += 0x7fffu + ((u>>16)&1u);           // RNE
  return (ushort)(u>>16);
}
__device__ __forceinline__ ushort4 cvt4(float4 v){
  ushort4 r; r.x=f2bf(v.x); r.y=f2bf(v.y); r.z=f2bf(v.z); r.w=f2bf(v.w); return r;
}
__device__ __forceinline__ bf16x8 cvt8(const float* p){
  union { bf16x8 v; ushort u[8]; } r;
  #pragma unroll
  for (int i=0;i<8;i++) r.u[i] = f2bf(p[i]);
  return r.v;
}
__device__ __forceinline__ floatx4 mfma16(bf16x8 a, bf16x8 b, floatx4 c){
  return __builtin_amdgcn_mfma_f32_16x16x32_bf16(a, b, c, 0, 0, 0);
}
// device-coherent (MALL-level) 16B load as 2x relaxed agent atomics: emits
// global_load_dwordx2 ... sc0 sc1 -> bypasses (possibly stale) per-XCD L2.
__device__ __forceinline__ bf16x8 ld16c(const ushort* p){
  union { bf16x8 v; u64 q[2]; } r;
  r.q[0] = __hip_atomic_load((const u64*)p,     __ATOMIC_RELAXED, __HIP_MEMORY_SCOPE_AGENT);
  r.q[1] = __hip_atomic_load((const u64*)p + 1, __ATOMIC_RELAXED, __HIP_MEMORY_SCOPE_AGENT);
  return r.v;
}
__device__ __forceinline__ void st8c(ushort* p, ushort4 s){
  union { ushort4 s4; u64 q; } u; u.s4 = s;
  __hip_atomic_store((u64*)p, u.q, __ATOMIC_RELAXED, __HIP_MEMORY_SCOPE_AGENT);
}

// ---------- setup: stable argsort(-seq_lens), zero barrier flags, write lens_s ----------
__global__ void k_setup(const int* __restrict__ slens, float* __restrict__ out,
                        uint* __restrict__ ws){
  for (int i = threadIdx.x; i < 1024; i += 256) ws[i] = 0u;   // barrier flags
  if (threadIdx.x == 0) {
    int len[32];
    for (int i=0;i<32;i++) len[i] = slens[i];
    int* ord  = (int*)((char*)ws + WS_ORD);
    int* lsrt = (int*)((char*)ws + WS_LENSB);
    uint used = 0;
    for (int i=0;i<32;i++){
      int best=-1, bl=-1;
      for (int j=0;j<32;j++)
        if (!((used>>j)&1u) && len[j] > bl){ bl=len[j]; best=j; }  // strict > => stable
      used |= 1u<<best;
      ord[i]=best; lsrt[i]=bl;
      out[OFF_LENS + i] = (float)bl;
    }
  }
}

// ---------- gathered 128x128-tile GEMM: x = (cnn@fc_w^T + b)[lut[ord]] * mask ----------
__launch_bounds__(256, 2)
__global__ void k_gemm(const float* __restrict__ Amat, const float* __restrict__ Bmat,
                       float* __restrict__ Cout, const float* __restrict__ bias1,
                       const int* __restrict__ lut, const uint* __restrict__ ws,
                       ushort* __restrict__ xbf){
  __shared__ ushort tA[128][32];
  __shared__ ushort tB[128][32];
  __shared__ int sOrd[32], sLen[32];
  const int tid = threadIdx.x, w = tid>>6, l = tid&63;
  const int m0 = blockIdx.y*128, n0 = blockIdx.x*128;
  {
    const int* ord  = (const int*)((const char*)ws + WS_ORD);
    const int* lsrt = (const int*)((const char*)ws + WS_LENSB);
    if (tid < 32){ sOrd[tid]=ord[tid]; sLen[tid]=lsrt[tid]; }
  }
  __syncthreads();
  const int maxlen = sLen[0];
  if ((m0>>5) >= maxlen){                 // rows m0..m0+127 all have t >= maxlen -> zeros
    float4 z; z.x=z.y=z.z=z.w=0.f;        // (xbf rows >= 32*maxlen are never read)
    for (int i = tid; i < 4096; i += 256){
      int row = i>>5, ch = i&31;
      *(float4*)&Cout[(size_t)(m0+row)*512 + n0 + ch*4] = z;
    }
    return;
  }
  const float* aP[4]; const float* bP[4];
  #pragma unroll
  for (int p=0;p<4;p++){
    int ra = m0 + p*32 + (tid>>3);
    int bb = ra & 31, tt = ra >> 5;
    aP[p] = Amat + (size_t)lut[sOrd[bb]*512 + tt]*2048 + (tid&7)*4;
    bP[p] = Bmat + (size_t)(n0 + p*32 + (tid>>3))*2048 + (tid&7)*4;
  }
  const floatx4 z4 = {0.f,0.f,0.f,0.f};
  floatx4 acc[4][4];
  #pragma unroll
  for (int a=0;a<4;a++)
    #pragma unroll
    for (int b=0;b<4;b++) acc[a][b] = z4;
  const int mh = (w&1)*64, nh = (w>>1)*64;
  for (int k0 = 0; k0 < 2048; k0 += 32){
    #pragma unroll
    for (int p=0;p<4;p++){
      float4 av = *(const float4*)(aP[p] + k0);
      float4 bv = *(const float4*)(bP[p] + k0);
      *(ushort4*)&tA[p*32 + (tid>>3)][(tid&7)*4] = cvt4(av);
      *(ushort4*)&tB[p*32 + (tid>>3)][(tid&7)*4] = cvt4(bv);
    }
    __syncthreads();
    bf16x8 af[4], bfv[4];
    #pragma unroll
    for (int mt=0;mt<4;mt++) af[mt]  = *(const bf16x8*)&tA[mh + mt*16 + (l&15)][(l>>4)*8];
    #pragma unroll
    for (int nt=0;nt<4;nt++) bfv[nt] = *(const bf16x8*)&tB[nh + nt*16 + (l&15)][(l>>4)*8];
    #pragma unroll
    for (int mt=0;mt<4;mt++)
      #pragma unroll
      for (int nt=0;nt<4;nt++)
        acc[mt][nt] = mfma16(af[mt], bfv[nt], acc[mt][nt]);
    __syncthreads();
  }
  #pragma unroll
  for (int mt=0;mt<4;mt++){
    #pragma unroll
    for (int nt=0;nt<4;nt++){
      const int gcol = n0 + nh + nt*16 + (l&15);
      const float bias = bias1[gcol];
      #pragma unroll
      for (int r=0;r<4;r++){
        const int grow = m0 + mh + mt*16 + (l>>4)*4 + r;
        float v = acc[mt][nt][r] + bias;
        int bb = grow & 31, tt = grow >> 5;
        if (tt >= sLen[bb]) v = 0.f;
        Cout[(size_t)grow*512 + gcol] = v;
        if (xbf) xbf[(size_t)grow*512 + gcol] = f2bf(v);
      }
    }
  }
}

// consumer side of the barrier: relaxed polls (NO acquire -> no L2 invalidates;
// all cross-WG data is read with L2-bypass atomics so it cannot be stale).
__device__ __forceinline__ void gwait(uint* flags, int tid, uint val){
  if (tid < 16){
    while (__hip_atomic_load(&flags[(size_t)tid*32], __ATOMIC_RELAXED, __HIP_MEMORY_SCOPE_AGENT) < val)
      __builtin_amdgcn_s_sleep(1);
  }
  __syncthreads();
}

// ---------- persistent BiLSTM recurrence: 32 WGs (16/dir) ----------
// Protocol per step: coherent h loads -> hh MFMA (x part pre-accumulated) ->
// LDS gate exchange -> elementwise -> coherent h store -> __syncthreads (drains
// vmcnt => h stores acked at coherence point) -> flag store (release) ->
// [overlap: out store + x-part MFMAs for t+1] -> relaxed poll.
template<int XBF>
__launch_bounds__(256, 1)
__global__ void k_lstm(const float* __restrict__ h0, const float* __restrict__ c0,
                       const float* __restrict__ wihF, const float* __restrict__ whhF,
                       const float* __restrict__ wihB, const float* __restrict__ whhB,
                       const float* __restrict__ bihF, const float* __restrict__ bhhF,
                       const float* __restrict__ bihB, const float* __restrict__ bhhB,
                       float* __restrict__ out, uint* __restrict__ ws,
                       const ushort* __restrict__ xbf){
  __shared__ float G[32][132];           // gates exchange, padded vs bank conflicts
  __shared__ int sLen[32];
  const int tid = threadIdx.x, q = tid>>6, l = tid&63;   // q = gate (i,f,g,o)
  const int dir = blockIdx.x & 1, g = blockIdx.x >> 1;   // g = H-slice [g*32, g*32+32)
  {
    const int* lsrt = (const int*)((const char*)ws + WS_LENSB);
    if (tid < 32) sLen[tid] = lsrt[tid];
  }
  __syncthreads();
  const float* wih = dir ? wihB : wihF;
  const float* whh = dir ? whhB : whhF;
  const float* bih = dir ? bihB : bihF;
  const float* bhh = dir ? bhhB : bhhF;
  const float* X  = out + OFF_X;         // fp32 x, row = t*32+b
  ushort* hbuf = (ushort*)((char*)ws + WS_HBUF) + (size_t)dir*32768;
  uint* flags = ws + (size_t)dir*512;    // 16 flags, 128B apart
  // resident weight B-fragments (bf16), rows q*512 + g*32 + [0,32), K=512 each
  bf16x8 wfi[2][16], wfh[2][16];
  #pragma unroll
  for (int tt=0; tt<2; tt++)
    #pragma unroll
    for (int kk=0; kk<16; kk++){
      const int row = q*512 + g*32 + tt*16 + (l&15);
      const size_t off = (size_t)row*512 + kk*32 + (l>>4)*8;
      wfi[tt][kk] = cvt8(wih + off);
      wfh[tt][kk] = cvt8(whh + off);
    }
  // elementwise ownership: thread -> (batch eb, 4 consecutive j in slice g)
  const int eb = tid>>3, jl = (tid&7)*4, jg = g*32 + jl;
  const int mylen = sLen[eb];
  const int smax  = sLen[0];             // sorted: max first
  const int lenA = sLen[l&15], lenB = sLen[16+(l&15)];   // for backward x reversal
  float bias[4][4];
  #pragma unroll
  for (int q2=0;q2<4;q2++)
    #pragma unroll
    for (int i=0;i<4;i++)
      bias[q2][i] = bih[q2*512 + jg + i] + bhh[q2*512 + jg + i];
  float cr[4], hp[4];
  const float* h0d = h0 + (size_t)dir*16384;
  const float* c0d = c0 + (size_t)dir*16384;
  #pragma unroll
  for (int i=0;i<4;i++){
    cr[i] = c0d[eb*512 + jg + i];
    hp[i] = h0d[eb*512 + jg + i];
  }
  // pre-stage bf16(h0) into hbuf slot 1 (read at t=0) -- coherent stores
  {
    ushort4 h4; h4.x=f2bf(hp[0]); h4.y=f2bf(hp[1]); h4.z=f2bf(hp[2]); h4.w=f2bf(hp[3]);
    st8c(&hbuf[16384 + eb*512 + jg], h4);
  }
  // zero the tail rows t in [smax, 512) of this WG's out slice (this dir's half)
  for (int idx = tid; idx < (512 - smax)*256; idx += 256){
    int row = smax + (idx >> 8), rem = idx & 255;
    int b = rem >> 3, jv = (rem & 7)*4;
    float4 zf; zf.x=zf.y=zf.z=zf.w=0.f;
    *(float4*)&out[(size_t)row*32768 + (size_t)b*1024 + (dir?512:0) + g*32 + jv] = zf;
  }
  const floatx4 z4 = {0.f,0.f,0.f,0.f};
  floatx4 a00, a01, a10, a11;            // gate accumulators (x-part preloaded)
  auto xpart = [&](int t){
    const int tA2 = dir ? (t < lenA ? lenA-1-t : t) : t;
    const int tB2 = dir ? (t < lenB ? lenB-1-t : t) : t;
    a00=z4; a01=z4; a10=z4; a11=z4;
    if constexpr (XBF){
      const ushort* xA = xbf + (size_t)(tA2*32 + (l&15))*512 + (l>>4)*8;
      const ushort* xB = xbf + (size_t)(tB2*32 + 16 + (l&15))*512 + (l>>4)*8;
      #pragma unroll
      for (int kk=0;kk<16;kk++){
        bf16x8 xf0 = *(const bf16x8*)(xA + kk*32);
        bf16x8 xf1 = *(const bf16x8*)(xB + kk*32);
        a00 = mfma16(xf0, wfi[0][kk], a00);
        a01 = mfma16(xf0, wfi[1][kk], a01);
        a10 = mfma16(xf1, wfi[0][kk], a10);
        a11 = mfma16(xf1, wfi[1][kk], a11);
      }
    } else {
      const float* xA = X + (size_t)(tA2*32 + (l&15))*512 + (l>>4)*8;
      const float* xB = X + (size_t)(tB2*32 + 16 + (l&15))*512 + (l>>4)*8;
      #pragma unroll
      for (int kk=0;kk<16;kk++){
        bf16x8 xf0 = cvt8(xA + kk*32);
        bf16x8 xf1 = cvt8(xB + kk*32);
        a00 = mfma16(xf0, wfi[0][kk], a00);
        a01 = mfma16(xf0, wfi[1][kk], a01);
        a10 = mfma16(xf1, wfi[0][kk], a10);
        a11 = mfma16(xf1, wfi[1][kk], a11);
      }
    }
  };
  __syncthreads();                       // h0 coherent stores drained (vmcnt 0)
  if (tid == 0)
    __hip_atomic_store(&flags[(size_t)g*32], 1u, __ATOMIC_RELEASE, __HIP_MEMORY_SCOPE_AGENT);
  xpart(0);                              // overlap with barrier skew
  gwait(flags, tid, 1u);
  for (int t=0; t<smax; ++t){
    const ushort* hsrc = hbuf + (size_t)((t+1)&1)*16384;
    // hh MFMAs: A fragments loaded with L2-bypass coherent loads (fresh data)
    {
      const ushort* hA = hsrc + (size_t)(l&15)*512      + (l>>4)*8;
      const ushort* hB = hsrc + (size_t)(16+(l&15))*512 + (l>>4)*8;
      #pragma unroll
      for (int kk=0;kk<16;kk++){
        bf16x8 hf0 = ld16c(hA + kk*32);
        bf16x8 hf1 = ld16c(hB + kk*32);
        a00 = mfma16(hf0, wfh[0][kk], a00);
        a01 = mfma16(hf0, wfh[1][kk], a01);
        a10 = mfma16(hf1, wfh[0][kk], a10);
        a11 = mfma16(hf1, wfh[1][kk], a11);
      }
    }
    #pragma unroll
    for (int r=0;r<4;r++){
      G[(l>>4)*4 + r     ][q*32      + (l&15)] = a00[r];
      G[(l>>4)*4 + r     ][q*32 + 16 + (l&15)] = a01[r];
      G[16 + (l>>4)*4 + r][q*32      + (l&15)] = a10[r];
      G[16 + (l>>4)*4 + r][q*32 + 16 + (l&15)] = a11[r];
    }
    __syncthreads();
    const bool m = t < mylen;
    float hnv[4], cnv[4];
    #pragma unroll
    for (int i=0;i<4;i++){
      float gi = G[eb][     jl+i] + bias[0][i];
      float gf = G[eb][32 + jl+i] + bias[1][i];
      float gg = G[eb][64 + jl+i] + bias[2][i];
      float go = G[eb][96 + jl+i] + bias[3][i];
      float si = 1.f/(1.f + __expf(-gi));
      float sf = 1.f/(1.f + __expf(-gf));
      float tg = 1.f - 2.f/(__expf(2.f*gg) + 1.f);
      float so = 1.f/(1.f + __expf(-go));
      float cn = sf*cr[i] + si*tg;
      float hn = so*(1.f - 2.f/(__expf(2.f*cn) + 1.f));
      hnv[i]=hn; cnv[i]=cn;
      if (m){ cr[i]=cn; hp[i]=hn; }      // carry held when masked
    }
    {
      ushort4 hb4; hb4.x=f2bf(hp[0]); hb4.y=f2bf(hp[1]); hb4.z=f2bf(hp[2]); hb4.w=f2bf(hp[3]);
      st8c(&hbuf[(size_t)(t&1)*16384 + eb*512 + jg], hb4);
    }
    __syncthreads();                     // all h stores acked at coherence point
    const bool more = (t+1 < smax);
    if (tid == 0 && more)
      __hip_atomic_store(&flags[(size_t)g*32], (uint)(t+2), __ATOMIC_RELEASE, __HIP_MEMORY_SCOPE_AGENT);
    // ---- overlap region: independent of other WGs ----
    float4 o4;
    if (m){ o4.x=hnv[0]; o4.y=hnv[1]; o4.z=hnv[2]; o4.w=hnv[3]; }
    else  { o4.x=0.f; o4.y=0.f; o4.z=0.f; o4.w=0.f; }
    const size_t orow = dir ? (size_t)(m ? (mylen-1-t) : t) : (size_t)t;
    *(float4*)&out[orow*32768 + (size_t)eb*1024 + (dir?512:0) + jg] = o4;
    if (t == mylen-1){
      float4 h4; h4.x=hnv[0]; h4.y=hnv[1]; h4.z=hnv[2]; h4.w=hnv[3];
      float4 c4; c4.x=cnv[0]; c4.y=cnv[1]; c4.z=cnv[2]; c4.w=cnv[3];
      *(float4*)&out[OFF_HN + (size_t)dir*16384 + eb*512 + jg] = h4;
      *(float4*)&out[OFF_CN + (size_t)dir*16384 + eb*512 + jg] = c4;
    }
    if (more){
      xpart(t+1);                        // x-part of next step hides barrier wait
      gwait(flags, tid, (uint)(t+2));
    }
  }
}

extern "C" void kernel_launch(void* const* d_in, const int* in_sizes, int n_in,
                              void* d_out, int out_size, void* d_ws, size_t ws_size,
                              hipStream_t stream) {
  const float* cnn  = (const float*)d_in[0];
  const float* fcw  = (const float*)d_in[1];
  const float* fcb  = (const float*)d_in[2];
  const float* h0   = (const float*)d_in[3];
  const float* c0   = (const float*)d_in[4];
  const float* wihf = (const float*)d_in[5];
  const float* whhf = (const float*)d_in[6];
  const float* bihf = (const float*)d_in[7];
  const float* bhhf = (const float*)d_in[8];
  const float* wihb = (const float*)d_in[9];
  const float* whhb = (const float*)d_in[10];
  const float* bihb = (const float*)d_in[11];
  const float* bhhb = (const float*)d_in[12];
  const int* slens  = (const int*)d_in[13];
  const int* lut    = (const int*)d_in[14];
  float* out = (float*)d_out;
  uint*  ws  = (uint*)d_ws;
  float* xout = out + OFF_X;

  const bool hasx = ws_size >= (size_t)WS_XBF + 16777216ull;
  ushort* xbf = hasx ? (ushort*)((char*)d_ws + WS_XBF) : (ushort*)nullptr;

  k_setup<<<1, 256, 0, stream>>>(slens, out, ws);
  k_gemm<<<dim3(4,128), 256, 0, stream>>>(cnn, fcw, xout, fcb, lut, ws, xbf);
  if (hasx)
    k_lstm<1><<<dim3(32), 256, 0, stream>>>(h0, c0, wihf, whhf, wihb, whhb,
                                            bihf, bhhf, bihb, bhhb, out, ws, xbf);
  else
    k_lstm<0><<<dim3(32), 256, 0, stream>>>(h0, c0, wihf, whhf, wihb, whhb,
                                            bihf, bhhf, bihb, bhhb, out, ws, nullptr);
  (void)in_sizes; (void)n_in; (void)out_size; (void)ws_size;
}